// Round 9
// baseline (52.095 us; speedup 1.0000x reference)
//
#include <hip/hip_runtime.h>
#include <math.h>

// ---------------- K0: WphiT[k][dd] = Wphi[dd][k] (128x512 fp32, 256 KB) ----
__global__ void transpose_wphi_k(const float* __restrict__ wphi,
                                 float* __restrict__ wphiT) {
  int idx = blockIdx.x * 256 + threadIdx.x;   // 0..65535
  int k  = idx >> 9;
  int dd = idx & 511;
  wphiT[idx] = wphi[dd * 128 + k];
}

__device__ __forceinline__ void fma4(float4& a, float s, const float4& w) {
  a.x = fmaf(s, w.x, a.x);
  a.y = fmaf(s, w.y, a.y);
  a.z = fmaf(s, w.z, a.z);
  a.w = fmaf(s, w.w, a.w);
}

__device__ __forceinline__ float wave_sum(float v) {
  v += __shfl_xor(v, 32, 64);
  v += __shfl_xor(v, 16, 64);
  v += __shfl_xor(v,  8, 64);
  v += __shfl_xor(v,  4, 64);
  v += __shfl_xor(v,  2, 64);
  v += __shfl_xor(v,  1, 64);
  return v;
}

// ---------------- K1: U[g] = (A[g].Wpsi).WphiT, 16 rows/block -------------
// 256 blocks x 512 thr. Weights read once per block, each load amortized
// over 8 rows (32 FMA/load). Partials in LDS. 104 KB LDS, 1 block/CU.
// LDS floats: As[16][512] @0 (32KB) | part @8192 (64KB) | Qs[16][128] @24576 (8KB)
__launch_bounds__(512, 1)
__global__ void proj_k(const float* __restrict__ A,      // (4096,512)
                       const float* __restrict__ Wpsi,   // (512,128)
                       const float* __restrict__ WphiT,  // (128,512)
                       float* __restrict__ U)            // (4096,512)
{
  __shared__ __align__(16) float S[26624];
  const int tid = threadIdx.x;
  const int g0  = blockIdx.x * 16;

  // ---- stage A: 16 rows flat, coalesced f4 ----
  {
    const float4* src = (const float4*)(A + (size_t)g0 * 512);
    float4* dst = (float4*)S;
#pragma unroll
    for (int j = 0; j < 4; ++j) dst[tid + j * 512] = src[tid + j * 512];
  }
  __syncthreads();

  // ---- phase Q: qpart[ds][r][k] over d-slice; thread=(kg,ds,rh) ----
  // kg = tid&31 (k f4), ds = (tid>>5)&7 (64 d's), rh = tid>>8 (8 rows)
  {
    const int kg = tid & 31;
    const int ds = (tid >> 5) & 7;
    const int rh = tid >> 8;
    float4 acc[8];
#pragma unroll
    for (int i = 0; i < 8; ++i) acc[i] = make_float4(0.f, 0.f, 0.f, 0.f);
    const float4* wp4 = (const float4*)Wpsi;
#pragma unroll 4
    for (int i = 0; i < 64; ++i) {
      const int d = ds * 64 + i;
      float4 w4 = wp4[d * 32 + kg];      // once per block per d: L2, 1:32 amortized
#pragma unroll
      for (int r = 0; r < 8; ++r) {
        float a = S[(rh * 8 + r) * 512 + d];   // 2-addr LDS broadcast (free)
        fma4(acc[r], a, w4);
      }
    }
    float4* qp4 = (float4*)(S + 8192);
#pragma unroll
    for (int r = 0; r < 8; ++r)
      qp4[(ds * 16 + rh * 8 + r) * 32 + kg] = acc[r];
  }
  __syncthreads();

  // ---- Q-reduce over 8 ds -> Qs[r][k] ----
  {
    const int r  = tid >> 5;
    const int kq = tid & 31;
    const float4* qp4 = (const float4*)(S + 8192);
    float4 s = make_float4(0.f, 0.f, 0.f, 0.f);
#pragma unroll
    for (int ds = 0; ds < 8; ++ds) {
      float4 p = qp4[(ds * 16 + r) * 32 + kq];
      s.x += p.x; s.y += p.y; s.z += p.z; s.w += p.w;
    }
    ((float4*)(S + 24576))[r * 32 + kq] = s;
  }
  __syncthreads();

  // ---- phase U: upart[kh][r][dd] over k-half; thread=(ddq,kh,rh) ----
  // ddq = tid&127 (dd f4), kh = (tid>>7)&1 (64 k's), rh = tid>>8 (8 rows)
  {
    const int ddq = tid & 127;
    const int kh  = (tid >> 7) & 1;
    const int rh  = tid >> 8;
    float4 acc[8];
#pragma unroll
    for (int i = 0; i < 8; ++i) acc[i] = make_float4(0.f, 0.f, 0.f, 0.f);
    const float4* wt4 = (const float4*)WphiT;
    const float* qs = S + 24576;
#pragma unroll 4
    for (int i = 0; i < 64; ++i) {
      const int k = kh * 64 + i;
      float4 w4 = wt4[k * 128 + ddq];     // 1 KB/wave coalesced, 1:32 amortized
#pragma unroll
      for (int r = 0; r < 8; ++r) {
        float q = qs[(rh * 8 + r) * 128 + k];   // uniform LDS broadcast
        fma4(acc[r], q, w4);
      }
    }
    float4* up4 = (float4*)(S + 8192);
#pragma unroll
    for (int r = 0; r < 8; ++r)
      up4[(kh * 16 + rh * 8 + r) * 128 + ddq] = acc[r];
  }
  __syncthreads();

  // ---- U-reduce over 2 kh + store to global (coalesced) ----
  {
    const float4* up4 = (const float4*)(S + 8192);
    float4* U4 = (float4*)U;
#pragma unroll
    for (int m = 0; m < 4; ++m) {
      const int idx = tid + m * 512;      // 0..2047
      const int r   = idx >> 7;
      const int ddq = idx & 127;
      float4 x = up4[r * 128 + ddq];
      float4 y = up4[(16 + r) * 128 + ddq];
      x.x += y.x; x.y += y.y; x.z += y.z; x.w += y.w;
      U4[(size_t)(g0 + r) * 128 + ddq] = x;
    }
  }
}

// ---------------- K2: minimal-footprint stream, 32 waves/CU ---------------
// 4096 blocks x 128 thr (2 waves). Wave w of block handles a = 8w..8w+7 of
// row g. ~50 VGPR, 64 B LDS -> 16 blocks/CU resident. XCD-swizzled so each
// XCD streams a contiguous 16 MB slice of V.
__launch_bounds__(128, 8)
__global__ void stream_k(const float* __restrict__ V,   // (4096,16,512)
                         const float* __restrict__ U,   // (4096,512)
                         float* __restrict__ Out)       // (4096,16)
{
  __shared__ float betaS[16];
  const int lane = threadIdx.x & 63;
  const int w    = threadIdx.x >> 6;            // 0..1
  const int bid  = blockIdx.x;
  const size_t g = (size_t)((bid & 7) * 512 + (bid >> 3));   // XCD swizzle

  const float4* ug = (const float4*)U + g * 128;
  const float4 uf0 = ug[lane];          // d = 4*lane   .. +3
  const float4 uf1 = ug[lane + 64];     // d = 256+4*lane .. +3

  const float4* vb = (const float4*)V + g * 2048 + (size_t)w * 1024;  // 8 a's

  float acc[8];
#pragma unroll
  for (int ag = 0; ag < 4; ++ag) {      // 2 a's per group, 4 loads in flight
    float4 lo0 = vb[(ag * 2 + 0) * 128 + lane];
    float4 hi0 = vb[(ag * 2 + 0) * 128 + 64 + lane];
    float4 lo1 = vb[(ag * 2 + 1) * 128 + lane];
    float4 hi1 = vb[(ag * 2 + 1) * 128 + 64 + lane];
    float s0;
    s0 = lo0.x * uf0.x;
    s0 = fmaf(lo0.y, uf0.y, s0);
    s0 = fmaf(lo0.z, uf0.z, s0);
    s0 = fmaf(lo0.w, uf0.w, s0);
    s0 = fmaf(hi0.x, uf1.x, s0);
    s0 = fmaf(hi0.y, uf1.y, s0);
    s0 = fmaf(hi0.z, uf1.z, s0);
    s0 = fmaf(hi0.w, uf1.w, s0);
    acc[ag * 2] = s0;
    float s1;
    s1 = lo1.x * uf0.x;
    s1 = fmaf(lo1.y, uf0.y, s1);
    s1 = fmaf(lo1.z, uf0.z, s1);
    s1 = fmaf(lo1.w, uf0.w, s1);
    s1 = fmaf(hi1.x, uf1.x, s1);
    s1 = fmaf(hi1.y, uf1.y, s1);
    s1 = fmaf(hi1.z, uf1.z, s1);
    s1 = fmaf(hi1.w, uf1.w, s1);
    acc[ag * 2 + 1] = s1;
  }

#pragma unroll
  for (int a = 0; a < 8; ++a) acc[a] = wave_sum(acc[a]);

  if (lane == 0) {
    betaS[w * 8 + 0] = acc[0];
    betaS[w * 8 + 1] = acc[1];
    betaS[w * 8 + 2] = acc[2];
    betaS[w * 8 + 3] = acc[3];
    betaS[w * 8 + 4] = acc[4];
    betaS[w * 8 + 5] = acc[5];
    betaS[w * 8 + 6] = acc[6];
    betaS[w * 8 + 7] = acc[7];
  }
  __syncthreads();

  if (w == 0 && lane == 0) {
    float mx = betaS[0];
#pragma unroll
    for (int a = 1; a < 16; ++a) mx = fmaxf(mx, betaS[a]);
    float ss = 0.f;
#pragma unroll
    for (int a = 0; a < 16; ++a) ss += __expf(betaS[a] - mx);
    const float inv = 1.0f / ss;
    float4* o4 = (float4*)(Out + g * 16);
#pragma unroll
    for (int qd = 0; qd < 4; ++qd) {
      o4[qd] = make_float4(__expf(betaS[qd*4+0] - mx) * inv,
                           __expf(betaS[qd*4+1] - mx) * inv,
                           __expf(betaS[qd*4+2] - mx) * inv,
                           __expf(betaS[qd*4+3] - mx) * inv);
    }
  }
}

extern "C" void kernel_launch(void* const* d_in, const int* in_sizes, int n_in,
                              void* d_out, int out_size, void* d_ws, size_t ws_size,
                              hipStream_t stream) {
  (void)in_sizes; (void)n_in; (void)out_size; (void)ws_size;
  const float* A    = (const float*)d_in[0];  // agent_observation (128,32,512)
  const float* V    = (const float*)d_in[1];  // visible_observations (128,32,16,512)
  const float* Wpsi = (const float*)d_in[2];  // (512,128)
  const float* Wphi = (const float*)d_in[3];  // (512,128)
  float* Out = (float*)d_out;                 // (4096,16) fp32

  float* WphiT = (float*)d_ws;                // 256 KB
  float* U     = (float*)d_ws + 65536;        // 8 MB

  transpose_wphi_k<<<256, 256, 0, stream>>>(Wphi, WphiT);
  proj_k<<<256, 512, 0, stream>>>(A, Wpsi, WphiT, U);
  stream_k<<<4096, 128, 0, stream>>>(V, U, Out);
}